// Round 7
// baseline (1015.518 us; speedup 1.0000x reference)
//
#include <hip/hip_runtime.h>

#define N_NODES 100000
#define N_EDGES 1600000
#define E_TOT   1700000   // edges + self loops
#define HEADS   8
#define CH      32
#define F       256       // HEADS*CH
#define NCHUNK  ((N_NODES + 255) / 256)   // 391

static __device__ __forceinline__ float lrelu(float v, float s) { return fmaxf(v, s * v); }

static __device__ __forceinline__ unsigned short f2bf(float f) {
    unsigned u = __float_as_uint(f);
    u += 0x7FFFu + ((u >> 16) & 1u);      // round-to-nearest-even
    return (unsigned short)(u >> 16);
}
static __device__ __forceinline__ float bf2f(unsigned short u) {
    return __uint_as_float(((unsigned)u) << 16);
}

// ======================= CSR build (once per call) =======================
__global__ __launch_bounds__(256) void k_deg_init(int* __restrict__ cnt, float* __restrict__ stats) {
    const int i = blockIdx.x * 256 + threadIdx.x;
    if (i < N_NODES) cnt[i] = 1;          // self loop
    if (blockIdx.x == 0 && threadIdx.x < 192) stats[threadIdx.x] = 0.f;
}

__global__ __launch_bounds__(256) void k_hist(const int* __restrict__ ei, int* __restrict__ cnt) {
    for (int e = blockIdx.x * 256 + threadIdx.x; e < N_EDGES; e += gridDim.x * 256)
        atomicAdd(&cnt[ei[N_EDGES + e]], 1);
}

__global__ __launch_bounds__(256) void k_scan_chunk(
    const int* __restrict__ cnt, int* __restrict__ row_start, int* __restrict__ csum)
{
    __shared__ int s[256];
    const int t = threadIdx.x;
    const int i = blockIdx.x * 256 + t;
    const int v = (i < N_NODES) ? cnt[i] : 0;
    s[t] = v;
    __syncthreads();
    for (int off = 1; off < 256; off <<= 1) {
        const int y = (t >= off) ? s[t - off] : 0;
        __syncthreads();
        s[t] += y;
        __syncthreads();
    }
    if (i < N_NODES) row_start[i] = s[t] - v;   // exclusive
    if (t == 255) csum[blockIdx.x] = s[t];
}

__global__ __launch_bounds__(512) void k_scan_top(int* __restrict__ csum) {
    __shared__ int s[512];
    const int t = threadIdx.x;
    const int v = (t < NCHUNK) ? csum[t] : 0;
    s[t] = v;
    __syncthreads();
    for (int off = 1; off < 512; off <<= 1) {
        const int y = (t >= off) ? s[t - off] : 0;
        __syncthreads();
        s[t] += y;
        __syncthreads();
    }
    if (t < NCHUNK) csum[t] = s[t] - v;         // exclusive
}

__global__ __launch_bounds__(256) void k_fill_init(
    int* __restrict__ row_start, const int* __restrict__ csum,
    int* __restrict__ cursor, int* __restrict__ csr_src)
{
    const int i = blockIdx.x * 256 + threadIdx.x;
    if (i >= N_NODES) return;
    const int rs = row_start[i] + csum[i >> 8];
    row_start[i] = rs;
    cursor[i] = rs + 1;
    csr_src[rs] = i * 64;                       // self loop first (pre-scaled: element offset)
}

__global__ __launch_bounds__(256) void k_fill(
    const int* __restrict__ ei, int* __restrict__ cursor, int* __restrict__ csr_src)
{
    for (int e = blockIdx.x * 256 + threadIdx.x; e < N_EDGES; e += gridDim.x * 256) {
        const int pos = atomicAdd(&cursor[ei[N_EDGES + e]], 1);
        csr_src[pos] = ei[e] * 64;              // pre-scaled: ushort4-element offset of row
    }
}
// after k_fill: cursor[i] == row_end[i]

// ====== xl = bn?(x) @ Wl (bf16), xr = bn?(x) @ Wr (bf16)  ([N,32]@[32,256]) ======
template <bool NORM>
__global__ __launch_bounds__(256) void k_gemm(
    const float* __restrict__ xin, const float* __restrict__ pstats,
    const float* __restrict__ pg, const float* __restrict__ pbe,
    const float* __restrict__ Wl, const float* __restrict__ Wr,
    unsigned short* __restrict__ xl, unsigned short* __restrict__ xr)
{
    __shared__ float xs[64 * CH];
    const int t = threadIdx.x;
    const int c = t & 31;
    float psc = 1.f, psh = 0.f;
    if (NORM) {
        const float mu  = pstats[c] * (1.f / N_NODES);
        const float var = pstats[32 + c] * (1.f / N_NODES) - mu * mu;
        psc = rsqrtf(var + 1e-5f) * pg[c];
        psh = pbe[c] - mu * psc;
    }
    float wl[CH], wr[CH];
#pragma unroll
    for (int k = 0; k < CH; ++k) {
        wl[k] = Wl[k * F + t];
        wr[k] = Wr[k * F + t];
    }
    for (int r0 = blockIdx.x * 64; r0 < N_NODES; r0 += gridDim.x * 64) {
        const int rows = min(64, N_NODES - r0);
        __syncthreads();
        for (int i = t; i < rows * CH; i += 256) {
            const float xv = xin[(size_t)r0 * CH + i];
            xs[i] = NORM ? fmaf(xv, psc, psh) : xv;
        }
        __syncthreads();
        for (int r = 0; r < rows; ++r) {
            float al = 0.f, ar = 0.f;
#pragma unroll
            for (int k = 0; k < CH; ++k) {
                const float xv = xs[r * CH + k];
                al = fmaf(xv, wl[k], al);
                ar = fmaf(xv, wr[k], ar);
            }
            xl[(size_t)(r0 + r) * F + t] = f2bf(al);
            xr[(size_t)(r0 + r) * F + t] = f2bf(ar);
        }
    }
}

// ============== single-pass GATv2 aggregation: one wave per dst node ==============
// lane l: head l>>3, channels 4*(l&7)..+3
// 4 gathers in flight (issued back-to-back), 2 independent accumulator chains
#define CHAIN(V, DEN, C0, C1, C2, C3)                                              \
    {                                                                              \
        const float x_ = bf2f(V.x), y_ = bf2f(V.y), z_ = bf2f(V.z), w_ = bf2f(V.w);\
        float s_ = lrelu(x_ + rx, 0.2f) * a4.x                                     \
                 + lrelu(y_ + ry, 0.2f) * a4.y                                     \
                 + lrelu(z_ + rz, 0.2f) * a4.z                                     \
                 + lrelu(w_ + rw, 0.2f) * a4.w;                                    \
        s_ += __shfl_xor(s_, 1);                                                   \
        s_ += __shfl_xor(s_, 2);                                                   \
        s_ += __shfl_xor(s_, 4);                                                   \
        const float p_ = __expf(s_);                                               \
        DEN += p_;                                                                 \
        C0 = fmaf(p_, x_, C0);                                                     \
        C1 = fmaf(p_, y_, C1);                                                     \
        C2 = fmaf(p_, z_, C2);                                                     \
        C3 = fmaf(p_, w_, C3);                                                     \
    }

__global__ __launch_bounds__(256) void k_agg(
    const int* __restrict__ row_start, const int* __restrict__ row_end,
    const int* __restrict__ csr_src, const unsigned short* __restrict__ xl,
    const unsigned short* __restrict__ xr, const float* __restrict__ att,
    float* __restrict__ accum)
{
    const int lane = threadIdx.x & 63;
    const int wid  = (blockIdx.x * blockDim.x + threadIdx.x) >> 6;
    const int nw   = (gridDim.x * blockDim.x) >> 6;
    const float4 a4 = ((const float4*)att)[lane];
    const ushort4* __restrict__ xl4 = (const ushort4*)xl;
    for (int n = wid; n < N_NODES; n += nw) {
        const ushort4 vru = ((const ushort4*)(xr + (size_t)n * F))[lane];
        const float rx = bf2f(vru.x), ry = bf2f(vru.y), rz = bf2f(vru.z), rw = bf2f(vru.w);
        float c0a = 0.f, c1a = 0.f, c2a = 0.f, c3a = 0.f, dena = 0.f;
        float c0b = 0.f, c1b = 0.f, c2b = 0.f, c3b = 0.f, denb = 0.f;
        const int e0 = row_start[n], e1 = row_end[n];
        int e = e0;
        for (; e + 3 < e1; e += 4) {
            // wave-uniform scalar loads of the 4 pre-scaled src offsets
            const unsigned oa = (unsigned)csr_src[e]     + (unsigned)lane;
            const unsigned ob = (unsigned)csr_src[e + 1] + (unsigned)lane;
            const unsigned oc = (unsigned)csr_src[e + 2] + (unsigned)lane;
            const unsigned od = (unsigned)csr_src[e + 3] + (unsigned)lane;
            // all four gathers issued before any use
            const ushort4 va = xl4[oa];
            const ushort4 vb = xl4[ob];
            const ushort4 vc = xl4[oc];
            const ushort4 vd = xl4[od];
            CHAIN(va, dena, c0a, c1a, c2a, c3a)
            CHAIN(vb, denb, c0b, c1b, c2b, c3b)
            CHAIN(vc, dena, c0a, c1a, c2a, c3a)
            CHAIN(vd, denb, c0b, c1b, c2b, c3b)
        }
        for (; e < e1; ++e) {
            const ushort4 va = xl4[(unsigned)csr_src[e] + (unsigned)lane];
            CHAIN(va, dena, c0a, c1a, c2a, c3a)
        }
        float c0 = c0a + c0b, c1 = c1a + c1b, c2 = c2a + c2b, c3 = c3a + c3b;
        const float inv = 0.125f / (dena + denb);   // alpha-normalize + head-mean
        c0 *= inv; c1 *= inv; c2 *= inv; c3 *= inv;
#pragma unroll
        for (int off = 8; off <= 32; off <<= 1) {   // sum the 8 heads
            c0 += __shfl_xor(c0, off);
            c1 += __shfl_xor(c1, off);
            c2 += __shfl_xor(c2, off);
            c3 += __shfl_xor(c3, off);
        }
        if (lane < 8)
            ((float4*)(accum + (size_t)n * CH))[lane] = make_float4(c0, c1, c2, c3);
    }
}

// ====== post: y = [lrelu](acc+bias) + residual(bn?(xprev)); batch stats ======
template <int MODE, bool NORM>   // MODE 0: leaky_relu 0.01 + residual, 1: residual only
__global__ __launch_bounds__(256) void k_post(
    float* __restrict__ y, const float* __restrict__ xprev,
    const float* __restrict__ pstats, const float* __restrict__ pg,
    const float* __restrict__ pbe, const float* __restrict__ bias,
    float* __restrict__ stats)
{
    __shared__ float s1[256], s2[256];
    const int t = threadIdx.x;
    const int c = t & 31;
    const float b = bias[c];
    float psc = 1.f, psh = 0.f;
    if (NORM) {
        const float mu  = pstats[c] * (1.f / N_NODES);
        const float var = pstats[32 + c] * (1.f / N_NODES) - mu * mu;
        psc = rsqrtf(var + 1e-5f) * pg[c];
        psh = pbe[c] - mu * psc;
    }
    float ls = 0.f, lq = 0.f;
    for (int i = blockIdx.x * 256 + t; i < N_NODES * CH; i += gridDim.x * 256) {
        float v = y[i] + b;
        if (MODE == 0) v = lrelu(v, 0.01f);
        const float xr_ = xprev[i];
        v += NORM ? fmaf(xr_, psc, psh) : xr_;
        y[i] = v;
        ls += v;
        lq = fmaf(v, v, lq);
    }
    s1[t] = ls; s2[t] = lq;
    __syncthreads();
    if (t < 32) {
        for (int j = 1; j < 8; ++j) { ls += s1[t + 32 * j]; lq += s2[t + 32 * j]; }
        atomicAdd(&stats[c], ls);
        atomicAdd(&stats[32 + c], lq);
    }
}

// ============== final batchnorm normalize → d_out ==============
__global__ __launch_bounds__(256) void k_bn(
    const float* __restrict__ y, const float* __restrict__ stats,
    const float* __restrict__ g, const float* __restrict__ be,
    float* __restrict__ xo)
{
    const int t = threadIdx.x;
    const int c = t & 31;
    const float mu  = stats[c] * (1.f / N_NODES);
    const float var = stats[32 + c] * (1.f / N_NODES) - mu * mu;
    const float sc  = rsqrtf(var + 1e-5f) * g[c];
    const float sh  = be[c] - mu * sc;
    for (int i = blockIdx.x * 256 + t; i < N_NODES * CH; i += gridDim.x * 256)
        xo[i] = fmaf(y[i], sc, sh);
}

extern "C" void kernel_launch(void* const* d_in, const int* in_sizes, int n_in,
                              void* d_out, int out_size, void* d_ws, size_t ws_size,
                              hipStream_t stream)
{
    const float* x0 = (const float*)d_in[0];
    const int*   ei = (const int*)d_in[1];

    char* ws = (char*)d_ws;
    unsigned short* xl    = (unsigned short*)ws;                          // N*256 bf16  51.2 MB
    unsigned short* xr    = xl + (size_t)N_NODES * F;                     // N*256 bf16  51.2 MB
    float*          accA  = (float*)(xr + (size_t)N_NODES * F);           // N*32  f32   12.8 MB
    float*          accB  = accA + (size_t)N_NODES * CH;                  // N*32  f32   12.8 MB
    float*          stats = accB + (size_t)N_NODES * CH;                  // 3*64
    int*            cnt   = (int*)(stats + 192);                          // N (cursor/row_end)
    int*            rowst = cnt + N_NODES;                                // N
    int*            csum  = rowst + N_NODES;                              // NCHUNK
    int*            csr   = csum + NCHUNK;                                // E_TOT  6.8 MB
    const size_t needed = (size_t)((char*)(csr + E_TOT) - ws);            // ~136 MB
    if (ws_size < needed) return;

    const float *Wl[3], *Wr[3], *att[3], *bb[3], *gg[3], *be[3];
    for (int L = 0; L < 3; ++L) {
        Wl[L]  = (const float*)d_in[3 + 6 * L + 0];
        Wr[L]  = (const float*)d_in[3 + 6 * L + 1];
        att[L] = (const float*)d_in[3 + 6 * L + 2];
        bb[L]  = (const float*)d_in[3 + 6 * L + 3];
        gg[L]  = (const float*)d_in[3 + 6 * L + 4];
        be[L]  = (const float*)d_in[3 + 6 * L + 5];
    }
    float* st0 = stats, *st1 = stats + 64, *st2 = stats + 128;

    // ---- CSR build (identical for all 3 layers) ----
    k_deg_init <<<NCHUNK, 256, 0, stream>>>(cnt, stats);
    k_hist     <<<1024,   256, 0, stream>>>(ei, cnt);
    k_scan_chunk<<<NCHUNK, 256, 0, stream>>>(cnt, rowst, csum);
    k_scan_top <<<1,      512, 0, stream>>>(csum);
    k_fill_init<<<NCHUNK, 256, 0, stream>>>(rowst, csum, cnt, csr);
    k_fill     <<<1024,   256, 0, stream>>>(ei, cnt, csr);

    // ---- layer 0: input x0 (raw) ----
    k_gemm<false><<<1563, 256, 0, stream>>>(x0, nullptr, nullptr, nullptr, Wl[0], Wr[0], xl, xr);
    k_agg        <<<2048, 256, 0, stream>>>(rowst, cnt, csr, xl, xr, att[0], accA);
    k_post<0, false><<<1024, 256, 0, stream>>>(accA, x0, nullptr, nullptr, nullptr, bb[0], st0);

    // ---- layer 1: input bn(accA; st0, g0, be0) ----
    k_gemm<true><<<1563, 256, 0, stream>>>(accA, st0, gg[0], be[0], Wl[1], Wr[1], xl, xr);
    k_agg       <<<2048, 256, 0, stream>>>(rowst, cnt, csr, xl, xr, att[1], accB);
    k_post<0, true><<<1024, 256, 0, stream>>>(accB, accA, st0, gg[0], be[0], bb[1], st1);

    // ---- layer 2: input bn(accB; st1, g1, be1) ----
    k_gemm<true><<<1563, 256, 0, stream>>>(accB, st1, gg[1], be[1], Wl[2], Wr[2], xl, xr);
    k_agg       <<<2048, 256, 0, stream>>>(rowst, cnt, csr, xl, xr, att[2], accA);
    k_post<1, true><<<1024, 256, 0, stream>>>(accA, accB, st1, gg[1], be[1], bb[2], st2);

    // ---- final BN -> d_out ----
    k_bn<<<2048, 256, 0, stream>>>(accA, st2, gg[2], be[2], (float*)d_out);

    (void)in_sizes; (void)n_in; (void)out_size;
}

// Round 8
// 950.592 us; speedup vs baseline: 1.0683x; 1.0683x over previous
//
#include <hip/hip_runtime.h>

#define N_NODES 100000
#define N_EDGES 1600000
#define E_TOT   1700000   // edges + self loops
#define HEADS   8
#define CH      32
#define F       256       // HEADS*CH
#define NCHUNK  ((N_NODES + 255) / 256)   // 391

static __device__ __forceinline__ float lrelu(float v, float s) { return fmaxf(v, s * v); }

static __device__ __forceinline__ unsigned short f2bf(float f) {
    unsigned u = __float_as_uint(f);
    u += 0x7FFFu + ((u >> 16) & 1u);      // round-to-nearest-even
    return (unsigned short)(u >> 16);
}
static __device__ __forceinline__ float bf2f(unsigned short u) {
    return __uint_as_float(((unsigned)u) << 16);
}

// ======================= CSR build (once per call) =======================
__global__ __launch_bounds__(256) void k_deg_init(int* __restrict__ cnt, float* __restrict__ stats) {
    const int i = blockIdx.x * 256 + threadIdx.x;
    if (i < N_NODES) cnt[i] = 1;          // self loop
    if (blockIdx.x == 0 && threadIdx.x < 192) stats[threadIdx.x] = 0.f;
}

__global__ __launch_bounds__(256) void k_hist(const int* __restrict__ ei, int* __restrict__ cnt) {
    for (int e = blockIdx.x * 256 + threadIdx.x; e < N_EDGES; e += gridDim.x * 256)
        atomicAdd(&cnt[ei[N_EDGES + e]], 1);
}

__global__ __launch_bounds__(256) void k_scan_chunk(
    const int* __restrict__ cnt, int* __restrict__ row_start, int* __restrict__ csum)
{
    __shared__ int s[256];
    const int t = threadIdx.x;
    const int i = blockIdx.x * 256 + t;
    const int v = (i < N_NODES) ? cnt[i] : 0;
    s[t] = v;
    __syncthreads();
    for (int off = 1; off < 256; off <<= 1) {
        const int y = (t >= off) ? s[t - off] : 0;
        __syncthreads();
        s[t] += y;
        __syncthreads();
    }
    if (i < N_NODES) row_start[i] = s[t] - v;   // exclusive
    if (t == 255) csum[blockIdx.x] = s[t];
}

__global__ __launch_bounds__(512) void k_scan_top(int* __restrict__ csum) {
    __shared__ int s[512];
    const int t = threadIdx.x;
    const int v = (t < NCHUNK) ? csum[t] : 0;
    s[t] = v;
    __syncthreads();
    for (int off = 1; off < 512; off <<= 1) {
        const int y = (t >= off) ? s[t - off] : 0;
        __syncthreads();
        s[t] += y;
        __syncthreads();
    }
    if (t < NCHUNK) csum[t] = s[t] - v;         // exclusive
}

__global__ __launch_bounds__(256) void k_fill_init(
    int* __restrict__ row_start, const int* __restrict__ csum,
    int* __restrict__ cursor, int* __restrict__ csr_src)
{
    const int i = blockIdx.x * 256 + threadIdx.x;
    if (i >= N_NODES) return;
    const int rs = row_start[i] + csum[i >> 8];
    row_start[i] = rs;
    cursor[i] = rs + 1;
    csr_src[rs] = i * 64;                       // self loop first (pre-scaled: ushort4-element offset)
}

__global__ __launch_bounds__(256) void k_fill(
    const int* __restrict__ ei, int* __restrict__ cursor, int* __restrict__ csr_src)
{
    for (int e = blockIdx.x * 256 + threadIdx.x; e < N_EDGES; e += gridDim.x * 256) {
        const int pos = atomicAdd(&cursor[ei[N_EDGES + e]], 1);
        csr_src[pos] = ei[e] * 64;              // pre-scaled
    }
}
// after k_fill: cursor[i] == row_end[i]

// ====== xl = bn?(x) @ Wl (bf16), xr = bn?(x) @ Wr (bf16)  ([N,32]@[32,256]) ======
template <bool NORM>
__global__ __launch_bounds__(256) void k_gemm(
    const float* __restrict__ xin, const float* __restrict__ pstats,
    const float* __restrict__ pg, const float* __restrict__ pbe,
    const float* __restrict__ Wl, const float* __restrict__ Wr,
    unsigned short* __restrict__ xl, unsigned short* __restrict__ xr)
{
    __shared__ float xs[64 * CH];
    const int t = threadIdx.x;
    const int c = t & 31;
    float psc = 1.f, psh = 0.f;
    if (NORM) {
        const float mu  = pstats[c] * (1.f / N_NODES);
        const float var = pstats[32 + c] * (1.f / N_NODES) - mu * mu;
        psc = rsqrtf(var + 1e-5f) * pg[c];
        psh = pbe[c] - mu * psc;
    }
    float wl[CH], wr[CH];
#pragma unroll
    for (int k = 0; k < CH; ++k) {
        wl[k] = Wl[k * F + t];
        wr[k] = Wr[k * F + t];
    }
    for (int r0 = blockIdx.x * 64; r0 < N_NODES; r0 += gridDim.x * 64) {
        const int rows = min(64, N_NODES - r0);
        __syncthreads();
        for (int i = t; i < rows * CH; i += 256) {
            const float xv = xin[(size_t)r0 * CH + i];
            xs[i] = NORM ? fmaf(xv, psc, psh) : xv;
        }
        __syncthreads();
        for (int r = 0; r < rows; ++r) {
            float al = 0.f, ar = 0.f;
#pragma unroll
            for (int k = 0; k < CH; ++k) {
                const float xv = xs[r * CH + k];
                al = fmaf(xv, wl[k], al);
                ar = fmaf(xv, wr[k], ar);
            }
            xl[(size_t)(r0 + r) * F + t] = f2bf(al);
            xr[(size_t)(r0 + r) * F + t] = f2bf(ar);
        }
    }
}

// ============== single-pass GATv2 aggregation: one wave per dst node ==============
// lane l: head l>>3, channels 4*(l&7)..+3
// EXACT round-5 structure: unroll-by-2, two independent chains, shfl_xor reduce.
__global__ __launch_bounds__(256) void k_agg(
    const int* __restrict__ row_start, const int* __restrict__ row_end,
    const int* __restrict__ csr_src, const unsigned short* __restrict__ xl,
    const unsigned short* __restrict__ xr, const float* __restrict__ att,
    float* __restrict__ accum)
{
    const int lane = threadIdx.x & 63;
    const int wid  = (blockIdx.x * blockDim.x + threadIdx.x) >> 6;
    const int nw   = (gridDim.x * blockDim.x) >> 6;
    const float4 a4 = ((const float4*)att)[lane];
    const ushort4* __restrict__ xl4 = (const ushort4*)xl;
    for (int n = wid; n < N_NODES; n += nw) {
        const ushort4 vru = ((const ushort4*)(xr + (size_t)n * F))[lane];
        const float rx = bf2f(vru.x), ry = bf2f(vru.y), rz = bf2f(vru.z), rw = bf2f(vru.w);
        float c0a = 0.f, c1a = 0.f, c2a = 0.f, c3a = 0.f, dena = 0.f;
        float c0b = 0.f, c1b = 0.f, c2b = 0.f, c3b = 0.f, denb = 0.f;
        const int e0 = row_start[n], e1 = row_end[n];
        int e = e0;
        for (; e + 1 < e1; e += 2) {
            const unsigned ia = (unsigned)csr_src[e]     + (unsigned)lane;
            const unsigned ib = (unsigned)csr_src[e + 1] + (unsigned)lane;
            const ushort4 va = xl4[ia];           // both loads issued before any use:
            const ushort4 vb = xl4[ib];           // two gathers in flight
            const float ax = bf2f(va.x), ay = bf2f(va.y), az = bf2f(va.z), aw = bf2f(va.w);
            const float bx = bf2f(vb.x), by = bf2f(vb.y), bz = bf2f(vb.z), bw = bf2f(vb.w);
            float sA = lrelu(ax + rx, 0.2f) * a4.x
                     + lrelu(ay + ry, 0.2f) * a4.y
                     + lrelu(az + rz, 0.2f) * a4.z
                     + lrelu(aw + rw, 0.2f) * a4.w;
            float sB = lrelu(bx + rx, 0.2f) * a4.x
                     + lrelu(by + ry, 0.2f) * a4.y
                     + lrelu(bz + rz, 0.2f) * a4.z
                     + lrelu(bw + rw, 0.2f) * a4.w;
            sA += __shfl_xor(sA, 1);  sB += __shfl_xor(sB, 1);
            sA += __shfl_xor(sA, 2);  sB += __shfl_xor(sB, 2);
            sA += __shfl_xor(sA, 4);  sB += __shfl_xor(sB, 4);
            const float pA = __expf(sA);
            const float pB = __expf(sB);
            dena += pA;                denb += pB;
            c0a = fmaf(pA, ax, c0a);   c0b = fmaf(pB, bx, c0b);
            c1a = fmaf(pA, ay, c1a);   c1b = fmaf(pB, by, c1b);
            c2a = fmaf(pA, az, c2a);   c2b = fmaf(pB, bz, c2b);
            c3a = fmaf(pA, aw, c3a);   c3b = fmaf(pB, bw, c3b);
        }
        if (e < e1) {                              // remainder edge
            const unsigned ia = (unsigned)csr_src[e] + (unsigned)lane;
            const ushort4 va = xl4[ia];
            const float ax = bf2f(va.x), ay = bf2f(va.y), az = bf2f(va.z), aw = bf2f(va.w);
            float sA = lrelu(ax + rx, 0.2f) * a4.x
                     + lrelu(ay + ry, 0.2f) * a4.y
                     + lrelu(az + rz, 0.2f) * a4.z
                     + lrelu(aw + rw, 0.2f) * a4.w;
            sA += __shfl_xor(sA, 1);
            sA += __shfl_xor(sA, 2);
            sA += __shfl_xor(sA, 4);
            const float pA = __expf(sA);
            dena += pA;
            c0a = fmaf(pA, ax, c0a);
            c1a = fmaf(pA, ay, c1a);
            c2a = fmaf(pA, az, c2a);
            c3a = fmaf(pA, aw, c3a);
        }
        float c0 = c0a + c0b, c1 = c1a + c1b, c2 = c2a + c2b, c3 = c3a + c3b;
        const float inv = 0.125f / (dena + denb);  // alpha-normalize + head-mean
        c0 *= inv; c1 *= inv; c2 *= inv; c3 *= inv;
#pragma unroll
        for (int off = 8; off <= 32; off <<= 1) {  // sum the 8 heads
            c0 += __shfl_xor(c0, off);
            c1 += __shfl_xor(c1, off);
            c2 += __shfl_xor(c2, off);
            c3 += __shfl_xor(c3, off);
        }
        if (lane < 8)
            ((float4*)(accum + (size_t)n * CH))[lane] = make_float4(c0, c1, c2, c3);
    }
}

// ====== post: y = [lrelu](acc+bias) + residual(bn?(xprev)); batch stats ======
template <int MODE, bool NORM>   // MODE 0: leaky_relu 0.01 + residual, 1: residual only
__global__ __launch_bounds__(256) void k_post(
    float* __restrict__ y, const float* __restrict__ xprev,
    const float* __restrict__ pstats, const float* __restrict__ pg,
    const float* __restrict__ pbe, const float* __restrict__ bias,
    float* __restrict__ stats)
{
    __shared__ float s1[256], s2[256];
    const int t = threadIdx.x;
    const int c = t & 31;
    const float b = bias[c];
    float psc = 1.f, psh = 0.f;
    if (NORM) {
        const float mu  = pstats[c] * (1.f / N_NODES);
        const float var = pstats[32 + c] * (1.f / N_NODES) - mu * mu;
        psc = rsqrtf(var + 1e-5f) * pg[c];
        psh = pbe[c] - mu * psc;
    }
    float ls = 0.f, lq = 0.f;
    for (int i = blockIdx.x * 256 + t; i < N_NODES * CH; i += gridDim.x * 256) {
        float v = y[i] + b;
        if (MODE == 0) v = lrelu(v, 0.01f);
        const float xr_ = xprev[i];
        v += NORM ? fmaf(xr_, psc, psh) : xr_;
        y[i] = v;
        ls += v;
        lq = fmaf(v, v, lq);
    }
    s1[t] = ls; s2[t] = lq;
    __syncthreads();
    if (t < 32) {
        for (int j = 1; j < 8; ++j) { ls += s1[t + 32 * j]; lq += s2[t + 32 * j]; }
        atomicAdd(&stats[c], ls);
        atomicAdd(&stats[32 + c], lq);
    }
}

// ============== final batchnorm normalize → d_out ==============
__global__ __launch_bounds__(256) void k_bn(
    const float* __restrict__ y, const float* __restrict__ stats,
    const float* __restrict__ g, const float* __restrict__ be,
    float* __restrict__ xo)
{
    const int t = threadIdx.x;
    const int c = t & 31;
    const float mu  = stats[c] * (1.f / N_NODES);
    const float var = stats[32 + c] * (1.f / N_NODES) - mu * mu;
    const float sc  = rsqrtf(var + 1e-5f) * g[c];
    const float sh  = be[c] - mu * sc;
    for (int i = blockIdx.x * 256 + t; i < N_NODES * CH; i += gridDim.x * 256)
        xo[i] = fmaf(y[i], sc, sh);
}

extern "C" void kernel_launch(void* const* d_in, const int* in_sizes, int n_in,
                              void* d_out, int out_size, void* d_ws, size_t ws_size,
                              hipStream_t stream)
{
    const float* x0 = (const float*)d_in[0];
    const int*   ei = (const int*)d_in[1];

    char* ws = (char*)d_ws;
    unsigned short* xl    = (unsigned short*)ws;                          // N*256 bf16  51.2 MB
    unsigned short* xr    = xl + (size_t)N_NODES * F;                     // N*256 bf16  51.2 MB
    float*          accA  = (float*)(xr + (size_t)N_NODES * F);           // N*32  f32   12.8 MB
    float*          accB  = accA + (size_t)N_NODES * CH;                  // N*32  f32   12.8 MB
    float*          stats = accB + (size_t)N_NODES * CH;                  // 3*64
    int*            cnt   = (int*)(stats + 192);                          // N (cursor/row_end)
    int*            rowst = cnt + N_NODES;                                // N
    int*            csum  = rowst + N_NODES;                              // NCHUNK
    int*            csr   = csum + NCHUNK;                                // E_TOT  6.8 MB
    const size_t needed = (size_t)((char*)(csr + E_TOT) - ws);            // ~136 MB
    if (ws_size < needed) return;

    const float *Wl[3], *Wr[3], *att[3], *bb[3], *gg[3], *be[3];
    for (int L = 0; L < 3; ++L) {
        Wl[L]  = (const float*)d_in[3 + 6 * L + 0];
        Wr[L]  = (const float*)d_in[3 + 6 * L + 1];
        att[L] = (const float*)d_in[3 + 6 * L + 2];
        bb[L]  = (const float*)d_in[3 + 6 * L + 3];
        gg[L]  = (const float*)d_in[3 + 6 * L + 4];
        be[L]  = (const float*)d_in[3 + 6 * L + 5];
    }
    float* st0 = stats, *st1 = stats + 64, *st2 = stats + 128;

    // ---- CSR build (identical for all 3 layers) ----
    k_deg_init <<<NCHUNK, 256, 0, stream>>>(cnt, stats);
    k_hist     <<<1024,   256, 0, stream>>>(ei, cnt);
    k_scan_chunk<<<NCHUNK, 256, 0, stream>>>(cnt, rowst, csum);
    k_scan_top <<<1,      512, 0, stream>>>(csum);
    k_fill_init<<<NCHUNK, 256, 0, stream>>>(rowst, csum, cnt, csr);
    k_fill     <<<1024,   256, 0, stream>>>(ei, cnt, csr);

    // ---- layer 0: input x0 (raw) ----
    k_gemm<false><<<1563, 256, 0, stream>>>(x0, nullptr, nullptr, nullptr, Wl[0], Wr[0], xl, xr);
    k_agg        <<<2048, 256, 0, stream>>>(rowst, cnt, csr, xl, xr, att[0], accA);
    k_post<0, false><<<1024, 256, 0, stream>>>(accA, x0, nullptr, nullptr, nullptr, bb[0], st0);

    // ---- layer 1: input bn(accA; st0, g0, be0) ----
    k_gemm<true><<<1563, 256, 0, stream>>>(accA, st0, gg[0], be[0], Wl[1], Wr[1], xl, xr);
    k_agg       <<<2048, 256, 0, stream>>>(rowst, cnt, csr, xl, xr, att[1], accB);
    k_post<0, true><<<1024, 256, 0, stream>>>(accB, accA, st0, gg[0], be[0], bb[1], st1);

    // ---- layer 2: input bn(accB; st1, g1, be1) ----
    k_gemm<true><<<1563, 256, 0, stream>>>(accB, st1, gg[1], be[1], Wl[2], Wr[2], xl, xr);
    k_agg       <<<2048, 256, 0, stream>>>(rowst, cnt, csr, xl, xr, att[2], accA);
    k_post<1, true><<<1024, 256, 0, stream>>>(accA, accB, st1, gg[1], be[1], bb[2], st2);

    // ---- final BN -> d_out ----
    k_bn<<<2048, 256, 0, stream>>>(accA, st2, gg[2], be[2], (float*)d_out);

    (void)in_sizes; (void)n_in; (void)out_size;
}